// Round 12
// baseline (482.011 us; speedup 1.0000x reference)
//
#include <hip/hip_runtime.h>

#define T_SZ 65536
#define K_SZ 2048
#define D_SZ 256

typedef unsigned short u16;
typedef _Float16 f16;
typedef f16 f16x8 __attribute__((ext_vector_type(8)));
typedef float f32x4 __attribute__((ext_vector_type(4)));

#define RINGCAP 1024

__device__ __forceinline__ int swz4(int r) { return (r & 3) ^ ((r >> 2) & 3); }

__device__ __forceinline__ float pairwise128_sq_v4(const float4* __restrict__ a4) {
#pragma clang fp contract(off)
  float4 va = a4[0], vb = a4[1];
  float r0 = va.x * va.x, r1 = va.y * va.y, r2 = va.z * va.z, r3 = va.w * va.w;
  float r4 = vb.x * vb.x, r5 = vb.y * vb.y, r6 = vb.z * vb.z, r7 = vb.w * vb.w;
#pragma unroll
  for (int i = 2; i < 32; i += 2) {
    float4 c = a4[i], d = a4[i + 1];
    r0 += c.x * c.x;
    r1 += c.y * c.y;
    r2 += c.z * c.z;
    r3 += c.w * c.w;
    r4 += d.x * d.x;
    r5 += d.y * d.y;
    r6 += d.z * d.z;
    r7 += d.w * d.w;
  }
  return ((r0 + r1) + (r2 + r3)) + ((r4 + r5) + (r6 + r7));
}

__device__ __forceinline__ float2 pairwise128_sq_abs_v4(const float4* __restrict__ a4) {
#pragma clang fp contract(off)
  float4 va = a4[0], vb = a4[1];
  float r0 = va.x * va.x, r1 = va.y * va.y, r2 = va.z * va.z, r3 = va.w * va.w;
  float r4 = vb.x * vb.x, r5 = vb.y * vb.y, r6 = vb.z * vb.z, r7 = vb.w * vb.w;
  float s0 = fabsf(va.x) + fabsf(va.y), s1 = fabsf(va.z) + fabsf(va.w);
  float s2 = fabsf(vb.x) + fabsf(vb.y), s3 = fabsf(vb.z) + fabsf(vb.w);
#pragma unroll
  for (int i = 2; i < 32; i += 2) {
    float4 c = a4[i], d = a4[i + 1];
    r0 += c.x * c.x;
    r1 += c.y * c.y;
    r2 += c.z * c.z;
    r3 += c.w * c.w;
    r4 += d.x * d.x;
    r5 += d.y * d.y;
    r6 += d.z * d.z;
    r7 += d.w * d.w;
    s0 += fabsf(c.x) + fabsf(c.y);
    s1 += fabsf(c.z) + fabsf(c.w);
    s2 += fabsf(d.x) + fabsf(d.y);
    s3 += fabsf(d.z) + fabsf(d.w);
  }
  float2 res;
  res.x = ((r0 + r1) + (r2 + r3)) + ((r4 + r5) + (r6 + r7));
  res.y = (s0 + s1) + (s2 + s3);
  return res;
}

__global__ void esq_kernel(const float* __restrict__ e, float* __restrict__ esq) {
  int k = blockIdx.x * 64 + threadIdx.x;
  const float4* er = reinterpret_cast<const float4*>(e + (size_t)k * D_SZ);
  esq[k] = pairwise128_sq_v4(er) + pairwise128_sq_v4(er + 32);
}

// E: fp32 rows -> pre-tiled, pre-swizzled fp16 image (RNE via v_cvt_f16_f32).
__global__ __launch_bounds__(256) void conv_e_kernel(const float* __restrict__ src,
                                                     u16* __restrict__ dst) {
  const int tile = blockIdx.x, tid = threadIdx.x;
  const float4* s4 = reinterpret_cast<const float4*>(src);
  u16* dt = dst + (size_t)tile * 32768;
#pragma unroll 1
  for (int it = 0; it < 16; ++it) {
    int idx = tid + it * 256;
    int G = idx & 3, row = (idx >> 2) & 127, step = idx >> 9;
    int srow = tile * 128 + row;
    int kb = step * 32 + 8 * (G ^ swz4(row));
    float4 a = s4[srow * 64 + (kb >> 2)];
    float4 b = s4[srow * 64 + (kb >> 2) + 1];
    float v[8] = {a.x, a.y, a.z, a.w, b.x, b.y, b.z, b.w};
    union { f16 h[8]; uint4 vec; } pk;
#pragma unroll
    for (int j = 0; j < 8; ++j) pk.h[j] = (f16)v[j];
    *reinterpret_cast<uint4*>(dt + (size_t)step * 4096 + row * 32 + G * 8) = pk.vec;
  }
}

__device__ __forceinline__ float exact_cross(const float4* __restrict__ x4,
                                             const float4* __restrict__ e4,
                                             int grow, int code) {
  const float4* xr = x4 + (size_t)grow * 64;
  const float4* er = e4 + (size_t)code * 64;
  float acc = 0.0f;
#pragma unroll 8
  for (int t = 0; t < 64; ++t) {
    float4 a = xr[t], b = er[t];
    acc = __builtin_fmaf(a.x, b.x, acc);
    acc = __builtin_fmaf(a.y, b.y, acc);
    acc = __builtin_fmaf(a.z, b.z, acc);
    acc = __builtin_fmaf(a.w, b.w, acc);
  }
  return acc;
}

// ============================================================================
// ABLATION PROBE (M1): R10's prologue + A-staging + B-prefetch + K-loop,
// byte-equivalent instruction mix, with the ENTIRE epilogue/ring/rescore/
// output replaced by asm sinks (rule #17: keeps acc + all loads live, zero
// added instructions). Same LDS footprint (38,912B via pad) and same
// __launch_bounds__ so occupancy matches R10. Grid 2048 = 2 passes over the
// data; writes scrap into `out`, which the real kernel later overwrites.
// Measurement: M1_true = (dur_total - FULL - conv/esq)/2.
// ============================================================================
__global__ __launch_bounds__(256, 4) void vq_gemm_probe(
    const float* __restrict__ x, const u16* __restrict__ Eh,
    float* __restrict__ outp) {
  __shared__ __align__(16) u16 As[8][64][32];  // 32KB
  __shared__ float pad_[1536];                 // +6KB -> 38,912B total (match R10)

  const int tid = threadIdx.x;
  const int lane = tid & 63;
  const int wm = (tid >> 6) >> 1, wn = (tid >> 6) & 1;
  const int rowbase = (blockIdx.x & 1023) * 64;

  if (tid == 0) pad_[0] = 1.0f;  // keep pad allocated

  const float4* x4 = reinterpret_cast<const float4*>(x);

  // A staging: identical to FULL (fp32->fp16 in-kernel conv into LDS)
  const float4* xt4 = x4 + (size_t)rowbase * 64;
#pragma unroll 2
  for (int it = 0; it < 8; ++it) {
    int idx = tid + it * 256;
    int G = idx & 3, row = (idx >> 2) & 63, ks = idx >> 8;
    int kb = ks * 32 + 8 * (G ^ swz4(row));
    float4 a = xt4[(size_t)row * 64 + (kb >> 2)];
    float4 b = xt4[(size_t)row * 64 + (kb >> 2) + 1];
    union { f16 h[8]; uint4 vec; } pk;
    pk.h[0] = (f16)a.x; pk.h[1] = (f16)a.y; pk.h[2] = (f16)a.z; pk.h[3] = (f16)a.w;
    pk.h[4] = (f16)b.x; pk.h[5] = (f16)b.y; pk.h[6] = (f16)b.z; pk.h[7] = (f16)b.w;
    *reinterpret_cast<uint4*>(&As[ks][row][G * 8]) = pk.vec;
  }

  int offA[2], offB[4];
#pragma unroll
  for (int mf = 0; mf < 2; ++mf) {
    const int row = wm * 32 + mf * 16 + (lane & 15);
    offA[mf] = row * 32 + (((lane >> 4) ^ swz4(row)) * 8);
  }
#pragma unroll
  for (int nf = 0; nf < 4; ++nf) {
    const int cl = wn * 64 + nf * 16 + (lane & 15);
    offB[nf] = cl * 32 + (((lane >> 4) ^ swz4(cl)) * 8);
  }

  f32x4 acc[2][4];
#pragma unroll
  for (int mf = 0; mf < 2; ++mf)
#pragma unroll
    for (int nf = 0; nf < 4; ++nf) acc[mf][nf] = (f32x4){0.f, 0.f, 0.f, 0.f};

  f16x8 bpf[2][4];
#pragma unroll
  for (int nf = 0; nf < 4; ++nf)
    bpf[0][nf] = *reinterpret_cast<const f16x8*>(Eh + offB[nf]);

  __syncthreads();

#pragma unroll 1
  for (int chunk = 0; chunk < 16; ++chunk) {
#pragma unroll
    for (int ks = 0; ks < 8; ++ks) {
      const int par = ks & 1;
      const int gsn = chunk * 8 + ks + 1;
      if (gsn < 128) {
        const u16* bg = Eh + (size_t)gsn * 4096;
#pragma unroll
        for (int nf = 0; nf < 4; ++nf)
          bpf[par ^ 1][nf] = *reinterpret_cast<const f16x8*>(bg + offB[nf]);
      }
      const u16* aa = &As[ks][0][0];
      f16x8 afr[2];
#pragma unroll
      for (int mf = 0; mf < 2; ++mf)
        afr[mf] = *reinterpret_cast<const f16x8*>(aa + offA[mf]);
#pragma unroll
      for (int mf = 0; mf < 2; ++mf)
#pragma unroll
        for (int nf = 0; nf < 4; ++nf)
          acc[mf][nf] = __builtin_amdgcn_mfma_f32_16x16x32_f16(
              afr[mf], bpf[par][nf], acc[mf][nf], 0, 0, 0);
    }
    // epilogue replaced by DCE-proof sinks (rule #17), then rezero like FULL
#pragma unroll
    for (int mf = 0; mf < 2; ++mf)
#pragma unroll
      for (int nf = 0; nf < 4; ++nf) {
        asm volatile("" ::"v"(acc[mf][nf][0]), "v"(acc[mf][nf][1]),
                     "v"(acc[mf][nf][2]), "v"(acc[mf][nf][3]));
        acc[mf][nf] = (f32x4){0.f, 0.f, 0.f, 0.f};
      }
  }
  // observable side effect (scrap; fully overwritten by the real kernel)
  outp[(size_t)blockIdx.x * 256 + tid] = pad_[0] + (float)lane;
}

// ============================================================================
// FULL kernel: R10 source, UNCHANGED (239-244us, passed, absmax 0.0).
// ============================================================================
__global__ __launch_bounds__(256, 4) void vq_mfma_kernel(
    const float* __restrict__ x, const float* __restrict__ e,
    const u16* __restrict__ Eh, const float* __restrict__ esq_g,
    float* __restrict__ out, float* __restrict__ outIdx) {
  __shared__ __align__(16) u16 As[8][64][32];  // 32KB: [ks][row][Gj]
  __shared__ float xsq_s[64], th_s[64];
  __shared__ unsigned rm1_u[64];
  __shared__ unsigned ring[RINGCAP];
  __shared__ unsigned long long ebest[64];
  __shared__ int fidx[64];
  __shared__ unsigned ringcnt;

  const int tid = threadIdx.x;
  const int lane = tid & 63;
  const int wm = (tid >> 6) >> 1, wn = (tid >> 6) & 1;
  const int rowbase = blockIdx.x * 64;

  if (tid == 0) ringcnt = 0;
  if (tid < 64) {
    ebest[tid] = ~0ull;
    rm1_u[tid] = 0x7F7FFFFFu;
  }

  const float4* x4 = reinterpret_cast<const float4*>(x);

  const float4* xt4 = x4 + (size_t)rowbase * 64;
#pragma unroll 2
  for (int it = 0; it < 8; ++it) {
    int idx = tid + it * 256;
    int G = idx & 3, row = (idx >> 2) & 63, ks = idx >> 8;
    int kb = ks * 32 + 8 * (G ^ swz4(row));
    float4 a = xt4[(size_t)row * 64 + (kb >> 2)];
    float4 b = xt4[(size_t)row * 64 + (kb >> 2) + 1];
    union { f16 h[8]; uint4 vec; } pk;
    pk.h[0] = (f16)a.x; pk.h[1] = (f16)a.y; pk.h[2] = (f16)a.z; pk.h[3] = (f16)a.w;
    pk.h[4] = (f16)b.x; pk.h[5] = (f16)b.y; pk.h[6] = (f16)b.z; pk.h[7] = (f16)b.w;
    *reinterpret_cast<uint4*>(&As[ks][row][G * 8]) = pk.vec;
  }

  if (tid < 64) {
    const float4* xr = x4 + (size_t)(rowbase + tid) * 64;
    float2 p0 = pairwise128_sq_abs_v4(xr);
    float2 p1 = pairwise128_sq_abs_v4(xr + 32);
    xsq_s[tid] = p0.x + p1.x;
    th_s[tid] = 4.0e-6f * (p0.y + p1.y) + 4.0e-4f;
  }

  int offA[2], offB[4];
#pragma unroll
  for (int mf = 0; mf < 2; ++mf) {
    const int row = wm * 32 + mf * 16 + (lane & 15);
    offA[mf] = row * 32 + (((lane >> 4) ^ swz4(row)) * 8);
  }
#pragma unroll
  for (int nf = 0; nf < 4; ++nf) {
    const int cl = wn * 64 + nf * 16 + (lane & 15);
    offB[nf] = cl * 32 + (((lane >> 4) ^ swz4(cl)) * 8);
  }

  f32x4 acc[2][4];
#pragma unroll
  for (int mf = 0; mf < 2; ++mf)
#pragma unroll
    for (int nf = 0; nf < 4; ++nf) acc[mf][nf] = (f32x4){0.f, 0.f, 0.f, 0.f};

  f16x8 bpf[2][4];
#pragma unroll
  for (int nf = 0; nf < 4; ++nf)
    bpf[0][nf] = *reinterpret_cast<const f16x8*>(Eh + offB[nf]);

  __syncthreads();

#pragma unroll 1
  for (int chunk = 0; chunk < 16; ++chunk) {
    float esq_c[4];
#pragma unroll
    for (int nf = 0; nf < 4; ++nf)
      esq_c[nf] = esq_g[chunk * 128 + wn * 64 + nf * 16 + (lane & 15)];
#pragma unroll
    for (int ks = 0; ks < 8; ++ks) {
      const int par = ks & 1;
      const int gsn = chunk * 8 + ks + 1;
      if (gsn < 128) {
        const u16* bg = Eh + (size_t)gsn * 4096;
#pragma unroll
        for (int nf = 0; nf < 4; ++nf)
          bpf[par ^ 1][nf] = *reinterpret_cast<const f16x8*>(bg + offB[nf]);
      }
      const u16* aa = &As[ks][0][0];
      f16x8 afr[2];
#pragma unroll
      for (int mf = 0; mf < 2; ++mf)
        afr[mf] = *reinterpret_cast<const f16x8*>(aa + offA[mf]);
#pragma unroll
      for (int mf = 0; mf < 2; ++mf)
#pragma unroll
        for (int nf = 0; nf < 4; ++nf)
          acc[mf][nf] = __builtin_amdgcn_mfma_f32_16x16x32_f16(
              afr[mf], bpf[par][nf], acc[mf][nf], 0, 0, 0);
    }
#pragma unroll
    for (int mf = 0; mf < 2; ++mf) {
#pragma unroll
      for (int rg = 0; rg < 4; ++rg) {
        const int row = wm * 32 + mf * 16 + (lane >> 4) * 4 + rg;
        const float xq = xsq_s[row];
        float dmin = 3.4e38f;
#pragma unroll
        for (int nf = 0; nf < 4; ++nf)
          dmin = fminf(dmin, (xq - 2.0f * acc[mf][nf][rg]) + esq_c[nf]);
        dmin = fminf(dmin, __shfl_xor(dmin, 1, 64));
        dmin = fminf(dmin, __shfl_xor(dmin, 2, 64));
        dmin = fminf(dmin, __shfl_xor(dmin, 4, 64));
        dmin = fminf(dmin, __shfl_xor(dmin, 8, 64));
        if ((lane & 15) == 0) atomicMin(&rm1_u[row], __float_as_uint(dmin));
      }
    }
    __syncthreads();
    const int cbase = chunk * 128 + wn * 64;
#pragma unroll
    for (int mf = 0; mf < 2; ++mf) {
#pragma unroll
      for (int rg = 0; rg < 4; ++rg) {
        const int row = wm * 32 + mf * 16 + (lane >> 4) * 4 + rg;
        const float xq = xsq_s[row];
        const float gate = __uint_as_float(rm1_u[row]) + th_s[row];
#pragma unroll
        for (int nf = 0; nf < 4; ++nf) {
          const float dv = (xq - 2.0f * acc[mf][nf][rg]) + esq_c[nf];
          if (dv <= gate) {
            unsigned slot = atomicAdd(&ringcnt, 1u);
            if (slot < RINGCAP)
              ring[slot] = ((unsigned)row << 11) |
                           (unsigned)(cbase + nf * 16 + (lane & 15));
          }
          acc[mf][nf][rg] = 0.0f;
        }
      }
    }
  }
  __syncthreads();

  const float4* e4 = reinterpret_cast<const float4*>(e);
  const unsigned cnt = ringcnt;
  if (cnt <= RINGCAP) {
    for (unsigned i = tid; i < cnt; i += 256) {
      const unsigned ent = ring[i];
      const int row = (int)(ent >> 11), code = (int)(ent & 2047u);
      const float cr = exact_cross(x4, e4, rowbase + row, code);
      const float d = (xsq_s[row] - 2.0f * cr) + esq_g[code];
      const unsigned long long key =
          (((unsigned long long)__float_as_uint(d)) << 32) | (unsigned)code;
      atomicMin(&ebest[row], key);
    }
  } else {
#pragma unroll 1
    for (int row = 0; row < 64; ++row) {
      for (int code = tid; code < K_SZ; code += 256) {
        const float cr = exact_cross(x4, e4, rowbase + row, code);
        const float d = (xsq_s[row] - 2.0f * cr) + esq_g[code];
        const unsigned long long key =
            (((unsigned long long)__float_as_uint(d)) << 32) | (unsigned)code;
        atomicMin(&ebest[row], key);
      }
    }
  }
  __syncthreads();
  if (tid < 64) fidx[tid] = (int)(ebest[tid] & 2047ull);
  __syncthreads();

  float4* out4 = reinterpret_cast<float4*>(out);
#pragma unroll 1
  for (int i = tid; i < 64 * 64; i += 256) {
    const int row = i >> 6, q = i & 63;
    const int idx = fidx[row];
    float4 xv = x4[(size_t)(rowbase + row) * 64 + q];
    float4 qv = e4[(size_t)idx * 64 + q];
    float4 o;
    o.x = xv.x + (qv.x - xv.x);
    o.y = xv.y + (qv.y - xv.y);
    o.z = xv.z + (qv.z - xv.z);
    o.w = xv.w + (qv.w - xv.w);
    out4[(size_t)(rowbase + row) * 64 + q] = o;
    if (q == 0) outIdx[rowbase + row] = (float)idx;
  }
}

extern "C" void kernel_launch(void* const* d_in, const int* in_sizes, int n_in,
                              void* d_out, int out_size, void* d_ws, size_t ws_size,
                              hipStream_t stream) {
  const float* x = (const float*)d_in[0];
  const float* e = (const float*)d_in[1];
  float* out = (float*)d_out;
  float* outIdx = out + (size_t)T_SZ * D_SZ;

  float* esq = (float*)d_ws;
  u16* Eh = (u16*)(esq + K_SZ);

  conv_e_kernel<<<K_SZ / 128, 256, 0, stream>>>(e, Eh);
  esq_kernel<<<K_SZ / 64, 64, 0, stream>>>(e, esq);
  // M1 ablation probe: 2 passes over the data, scrap output (overwritten by
  // the real kernel below). M1_true = (total - FULL - ~20us) / 2.
  vq_gemm_probe<<<2048, 256, 0, stream>>>(x, Eh, out);
  // FULL (R10-identical): produces the actual result.
  vq_mfma_kernel<<<T_SZ / 64, 256, 0, stream>>>(x, e, Eh, esq, out, outIdx);
}